// Round 2
// baseline (71.739 us; speedup 1.0000x reference)
//
#include <hip/hip_runtime.h>

#define NPTS 16384
#define KS   16              // packed K slots per point (bf16)
#define BT   256
#define WPT  4               // waves per block
#define WRT  2               // 32-row tiles per wave
#define BROWS (WPT * WRT * 32)   // 256 rows per block
#define TSPLIT 8
#define SWEEP (NPTS / TSPLIT)    // 2048 targets per block sweep
#define NTILE (SWEEP / 32)       // 64 target tiles

typedef __attribute__((ext_vector_type(8)))  short  bf16x8;
typedef __attribute__((ext_vector_type(16))) float  f32x16;

__device__ __forceinline__ unsigned short btrunc(float f) {
    return (unsigned short)(__float_as_uint(f) >> 16);       // truncate to bf16 bits
}
__device__ __forceinline__ float btruncf(float f) {
    return __uint_as_float(__float_as_uint(f) & 0xFFFF0000u); // value of bf16 truncation
}

// Build MFMA-ready packs for both clouds, both roles.
// A-role (source rows):  [-2xh, -2xl, -2xh, -2yh, -2yl, -2yh, -2zh, -2zl, -2zh, 1, 1, 0...]
// B-role (target cols):  [ xh ,  xh ,  xl ,  yh ,  yh ,  yl ,  zh ,  zh ,  zl , q_h, q_l, 0...]
// so that A.B = -2*s.t + |t|^2  (lo*lo cross terms dropped: ~2^-16 relative).
__global__ void chamfer_pack(const float* __restrict__ s,
                             const float* __restrict__ t,
                             unsigned short* __restrict__ Apack,
                             unsigned short* __restrict__ Bpack,
                             float* __restrict__ sq)
{
    int i = blockIdx.x * blockDim.x + threadIdx.x;
    if (i >= 2 * NPTS) return;
    int cloud = i >> 14;                 // NPTS = 2^14
    int p = i & (NPTS - 1);
    const float* base = cloud ? t : s;
    float x = base[3 * p], y = base[3 * p + 1], z = base[3 * p + 2];

    float xh = btruncf(x), yh = btruncf(y), zh = btruncf(z);
    float xl = x - xh, yl = y - yh, zl = z - zh;
    float q = x * x + y * y + z * z;
    float qh = btruncf(q), ql = q - qh;

    unsigned short* A = Apack + (size_t)i * KS;
    unsigned short* B = Bpack + (size_t)i * KS;

    A[0] = btrunc(-2.f * xh); A[1] = btrunc(-2.f * xl); A[2] = A[0];
    A[3] = btrunc(-2.f * yh); A[4] = btrunc(-2.f * yl); A[5] = A[3];
    A[6] = btrunc(-2.f * zh); A[7] = btrunc(-2.f * zl); A[8] = A[6];
    A[9] = btrunc(1.0f);      A[10] = A[9];
    A[11] = A[12] = A[13] = A[14] = A[15] = 0;

    B[0] = btrunc(xh); B[1] = B[0]; B[2] = btrunc(xl);
    B[3] = btrunc(yh); B[4] = B[3]; B[5] = btrunc(yl);
    B[6] = btrunc(zh); B[7] = B[6]; B[8] = btrunc(zl);
    B[9] = btrunc(qh); B[10] = btrunc(ql);
    B[11] = B[12] = B[13] = B[14] = B[15] = 0;

    sq[i] = q;
}

// grid = (NPTS/BROWS, TSPLIT, 2). Each wave owns WRT 32-row tiles and sweeps
// SWEEP targets via 32x32x16 bf16 MFMA; per-output running min in VGPRs.
__global__ __launch_bounds__(BT, 4)
void chamfer_mfma(const unsigned short* __restrict__ Apack,
                  const unsigned short* __restrict__ Bpack,
                  const float* __restrict__ sq,
                  unsigned* __restrict__ out)
{
    const int dir = blockIdx.z;
    const unsigned short* A = Apack + (size_t)(dir ? NPTS : 0) * KS;
    const unsigned short* B = Bpack + (size_t)(dir ? 0 : NPTS) * KS;
    const float* s2 = sq + (dir ? NPTS : 0);
    unsigned* o = out + dir * NPTS;

    const int lane  = threadIdx.x & 63;
    const int wv    = threadIdx.x >> 6;
    const int n32   = lane & 31;
    const int khalf = lane >> 5;

    const int rbase = blockIdx.x * BROWS + wv * (WRT * 32);

    bf16x8 a[WRT];
#pragma unroll
    for (int rt = 0; rt < WRT; ++rt)
        a[rt] = *(const bf16x8*)(A + (size_t)(rbase + rt * 32 + n32) * KS + khalf * 8);

    f32x16 mn[WRT];
#pragma unroll
    for (int rt = 0; rt < WRT; ++rt)
#pragma unroll
        for (int r = 0; r < 16; ++r) mn[rt][r] = 1e30f;

    const int t0 = blockIdx.y * SWEEP;
    const f32x16 zc = {};

    bf16x8 b = *(const bf16x8*)(B + (size_t)(t0 + n32) * KS + khalf * 8);
    for (int t = 0; t < NTILE; ++t) {
        int tn = (t + 1 < NTILE) ? t + 1 : t;
        bf16x8 bn = *(const bf16x8*)(B + (size_t)(t0 + tn * 32 + n32) * KS + khalf * 8);
#pragma unroll
        for (int rt = 0; rt < WRT; ++rt) {
            f32x16 c = __builtin_amdgcn_mfma_f32_32x32x16_bf16(a[rt], b, zc, 0, 0, 0);
#pragma unroll
            for (int r = 0; r < 16; ++r) mn[rt][r] = fminf(mn[rt][r], c[r]);
        }
        b = bn;
    }

    // min across the 32 columns (lanes of each 32-group)
#pragma unroll
    for (int rt = 0; rt < WRT; ++rt) {
#pragma unroll
        for (int r = 0; r < 16; ++r) {
            float v = mn[rt][r];
            v = fminf(v, __shfl_xor(v, 1, 32));
            v = fminf(v, __shfl_xor(v, 2, 32));
            v = fminf(v, __shfl_xor(v, 4, 32));
            v = fminf(v, __shfl_xor(v, 8, 32));
            v = fminf(v, __shfl_xor(v, 16, 32));
            mn[rt][r] = v;
        }
    }

    if (n32 == 0) {
#pragma unroll
        for (int rt = 0; rt < WRT; ++rt)
#pragma unroll
            for (int r = 0; r < 16; ++r) {
                int row = rbase + rt * 32 + (r & 3) + 8 * (r >> 2) + 4 * khalf;
                float dist = fmaxf(mn[rt][r] + s2[row], 0.0f);
                atomicMin(&o[row], __float_as_uint(dist));
            }
    }
}

extern "C" void kernel_launch(void* const* d_in, const int* in_sizes, int n_in,
                              void* d_out, int out_size, void* d_ws, size_t ws_size,
                              hipStream_t stream) {
    const float* s = (const float*)d_in[0];
    const float* t = (const float*)d_in[1];

    unsigned short* Apack = (unsigned short*)d_ws;                 // 2*NPTS*KS ushort = 1 MB
    unsigned short* Bpack = Apack + (size_t)2 * NPTS * KS;         // 1 MB
    float* sq = (float*)(Bpack + (size_t)2 * NPTS * KS);           // 128 KB

    chamfer_pack<<<(2 * NPTS + BT - 1) / BT, BT, 0, stream>>>(s, t, Apack, Bpack, sq);

    // init outputs to huge positive float (bytes 0x7F -> ~3.39e38)
    hipMemsetAsync(d_out, 0x7F, (size_t)out_size * sizeof(float), stream);

    dim3 grid(NPTS / BROWS, TSPLIT, 2);
    chamfer_mfma<<<grid, BT, 0, stream>>>(Apack, Bpack, sq, (unsigned*)d_out);
}

// Round 3
// 47.718 us; speedup vs baseline: 1.5034x; 1.5034x over previous
//
#include <hip/hip_runtime.h>

#define NPTS 16384
#define KS   16                  // stored bf16 k-slots per point (32 B)
#define BT   256                 // 4 waves per block
#define RT   4                   // 16-row tiles per wave -> 64 rows/wave
#define BROWS 256                // rows per block (4 waves * 64)
#define TSPLIT 16
#define SWEEP (NPTS / TSPLIT)    // 1024 targets per block sweep
#define NTILE (SWEEP / 16)       // 64 16-target tiles

typedef __attribute__((ext_vector_type(8))) short bf16x8;
typedef __attribute__((ext_vector_type(4))) float f32x4;

__device__ __forceinline__ unsigned short btrunc(float f) {
    return (unsigned short)(__float_as_uint(f) >> 16);
}
__device__ __forceinline__ float btruncf(float f) {
    return __uint_as_float(__float_as_uint(f) & 0xFFFF0000u);
}

// A-role (source rows):  [-2xh, -2xl, -2xh, -2yh, -2yl, -2yh, -2zh, -2zl, -2zh, 1, 1, 0...]
// B-role (target cols):  [ xh ,  xh ,  xl ,  yh ,  yh ,  yl ,  zh ,  zh ,  zl , qh, ql, 0...]
// A(s).B(t) = -2 s.t + |t|^2   (lo*lo cross terms dropped, ~2^-16 relative)
__global__ void chamfer_pack(const float* __restrict__ s,
                             const float* __restrict__ t,
                             unsigned short* __restrict__ Apack,
                             unsigned short* __restrict__ Bpack,
                             float* __restrict__ sq)
{
    int i = blockIdx.x * blockDim.x + threadIdx.x;
    if (i >= 2 * NPTS) return;
    int cloud = i >> 14;
    int p = i & (NPTS - 1);
    const float* base = cloud ? t : s;
    float x = base[3 * p], y = base[3 * p + 1], z = base[3 * p + 2];

    float xh = btruncf(x), yh = btruncf(y), zh = btruncf(z);
    float xl = x - xh, yl = y - yh, zl = z - zh;
    float q = x * x + y * y + z * z;
    float qh = btruncf(q), ql = q - qh;

    unsigned short* A = Apack + (size_t)i * KS;
    unsigned short* B = Bpack + (size_t)i * KS;

    A[0] = btrunc(-2.f * xh); A[1] = btrunc(-2.f * xl); A[2] = A[0];
    A[3] = btrunc(-2.f * yh); A[4] = btrunc(-2.f * yl); A[5] = A[3];
    A[6] = btrunc(-2.f * zh); A[7] = btrunc(-2.f * zl); A[8] = A[6];
    A[9] = btrunc(1.0f);      A[10] = A[9];
    A[11] = A[12] = A[13] = A[14] = A[15] = 0;

    B[0] = btrunc(xh); B[1] = B[0]; B[2] = btrunc(xl);
    B[3] = btrunc(yh); B[4] = B[3]; B[5] = btrunc(yl);
    B[6] = btrunc(zh); B[7] = B[6]; B[8] = btrunc(zl);
    B[9] = btrunc(qh); B[10] = btrunc(ql);
    B[11] = B[12] = B[13] = B[14] = B[15] = 0;

    sq[i] = q;
}

// grid = (NPTS/BROWS=64, TSPLIT=16, 2). Wave: RT 16-row tiles x 1024-target sweep.
// 16x16x32 MFMA with k-slice duplication (lanes g>=2 reuse slice g&1) -> output = 2*(-2 s.t + |t|^2).
__global__ __launch_bounds__(BT, 4)
void chamfer_mfma(const unsigned short* __restrict__ Apack,
                  const unsigned short* __restrict__ Bpack,
                  const float* __restrict__ sq,
                  unsigned* __restrict__ out)
{
    const int dir = blockIdx.z;
    const unsigned short* A = Apack + (size_t)(dir ? NPTS : 0) * KS;
    const unsigned short* B = Bpack + (size_t)(dir ? 0 : NPTS) * KS;
    const float* s2 = sq + (dir ? NPTS : 0);
    unsigned* o = out + dir * NPTS;

    const int lane = threadIdx.x & 63;
    const int wv   = threadIdx.x >> 6;
    const int c16  = lane & 15;
    const int g    = lane >> 4;      // 0..3
    const int gh   = g & 1;          // duplicated k-slice

    const int rbase = blockIdx.x * BROWS + wv * (RT * 16);

    bf16x8 a[RT];
#pragma unroll
    for (int rt = 0; rt < RT; ++rt)
        a[rt] = *(const bf16x8*)(A + (size_t)(rbase + rt * 16 + c16) * KS + gh * 8);

    f32x4 mn[RT];
#pragma unroll
    for (int rt = 0; rt < RT; ++rt)
        mn[rt] = (f32x4){1e30f, 1e30f, 1e30f, 1e30f};

    const f32x4 zc = {};
    const unsigned short* Bl = B + (size_t)(blockIdx.y * SWEEP + c16) * KS + gh * 8;

#pragma unroll 4
    for (int t = 0; t < NTILE; ++t) {
        bf16x8 b = *(const bf16x8*)(Bl + (size_t)t * 16 * KS);
#pragma unroll
        for (int rt = 0; rt < RT; ++rt) {
            f32x4 c = __builtin_amdgcn_mfma_f32_16x16x32_bf16(a[rt], b, zc, 0, 0, 0);
            mn[rt][0] = fminf(mn[rt][0], c[0]);
            mn[rt][1] = fminf(mn[rt][1], c[1]);
            mn[rt][2] = fminf(mn[rt][2], c[2]);
            mn[rt][3] = fminf(mn[rt][3], c[3]);
        }
    }

    // C/D map (16x16x32): col = lane&15, row = g*4 + reg. Min across 16 cols.
#pragma unroll
    for (int rt = 0; rt < RT; ++rt) {
#pragma unroll
        for (int r = 0; r < 4; ++r) {
            float v = mn[rt][r];
            v = fminf(v, __shfl_xor(v, 1, 16));
            v = fminf(v, __shfl_xor(v, 2, 16));
            v = fminf(v, __shfl_xor(v, 4, 16));
            v = fminf(v, __shfl_xor(v, 8, 16));
            if (c16 == 0) {
                int row = rbase + rt * 16 + g * 4 + r;
                float dist = fmaxf(fmaf(0.5f, v, s2[row]), 0.0f);  // mn is 2x
                atomicMin(&o[row], __float_as_uint(dist));
            }
        }
    }
}

extern "C" void kernel_launch(void* const* d_in, const int* in_sizes, int n_in,
                              void* d_out, int out_size, void* d_ws, size_t ws_size,
                              hipStream_t stream) {
    const float* s = (const float*)d_in[0];
    const float* t = (const float*)d_in[1];

    unsigned short* Apack = (unsigned short*)d_ws;                 // 1 MB
    unsigned short* Bpack = Apack + (size_t)2 * NPTS * KS;         // 1 MB
    float* sq = (float*)(Bpack + (size_t)2 * NPTS * KS);           // 128 KB

    chamfer_pack<<<(2 * NPTS + BT - 1) / BT, BT, 0, stream>>>(s, t, Apack, Bpack, sq);

    hipMemsetAsync(d_out, 0x7F, (size_t)out_size * sizeof(float), stream);

    dim3 grid(NPTS / BROWS, TSPLIT, 2);
    chamfer_mfma<<<grid, BT, 0, stream>>>(Apack, Bpack, sq, (unsigned*)d_out);
}

// Round 5
// 35.969 us; speedup vs baseline: 1.9944x; 1.3266x over previous
//
#include <hip/hip_runtime.h>

#define NPTS 16384
#define KS   16                  // stored bf16 k-slots per point (32 B)
#define BT   256                 // 4 waves per block
#define BROWS 256                // rows per block: 4 waves x 2 32-row tiles
#define TSPLIT 8
#define SWEEP (NPTS / TSPLIT)    // 2048 targets per block sweep
#define NTILE (SWEEP / 32)       // 64 32-target tiles

typedef __attribute__((ext_vector_type(8)))  short bf16x8;
typedef __attribute__((ext_vector_type(16))) float f32x16;

__device__ __forceinline__ unsigned short btrunc(float f) {
    return (unsigned short)(__float_as_uint(f) >> 16);
}
__device__ __forceinline__ float btruncf(float f) {
    return __uint_as_float(__float_as_uint(f) & 0xFFFF0000u);
}

// A-role (source rows):  [-2xh, -2xl, -2xh, -2yh, -2yl, -2yh, -2zh, -2zl, -2zh, 1, 1, 0...]
// B-role (target cols):  [ xh ,  xh ,  xl ,  yh ,  yh ,  yl ,  zh ,  zh ,  zl , qh, ql, 0...]
// A(s).B(t) = -2 s.t + |t|^2   (lo*lo cross terms dropped, ~2^-16 relative)
__global__ void chamfer_pack(const float* __restrict__ s,
                             const float* __restrict__ t,
                             unsigned short* __restrict__ Apack,
                             unsigned short* __restrict__ Bpack,
                             float* __restrict__ sq,
                             unsigned* __restrict__ outinit)
{
    int i = blockIdx.x * blockDim.x + threadIdx.x;
    if (i >= 2 * NPTS) return;
    outinit[i] = 0x7F7F7F7Fu;            // huge positive float; out_size == 2*NPTS
    int cloud = i >> 14;
    int p = i & (NPTS - 1);
    const float* base = cloud ? t : s;
    float x = base[3 * p], y = base[3 * p + 1], z = base[3 * p + 2];

    float xh = btruncf(x), yh = btruncf(y), zh = btruncf(z);
    float xl = x - xh, yl = y - yh, zl = z - zh;
    float q = x * x + y * y + z * z;
    float qh = btruncf(q), ql = q - qh;

    unsigned short* A = Apack + (size_t)i * KS;
    unsigned short* B = Bpack + (size_t)i * KS;

    A[0] = btrunc(-2.f * xh); A[1] = btrunc(-2.f * xl); A[2] = A[0];
    A[3] = btrunc(-2.f * yh); A[4] = btrunc(-2.f * yl); A[5] = A[3];
    A[6] = btrunc(-2.f * zh); A[7] = btrunc(-2.f * zl); A[8] = A[6];
    A[9] = btrunc(1.0f);      A[10] = A[9];
    A[11] = A[12] = A[13] = A[14] = A[15] = 0;

    B[0] = btrunc(xh); B[1] = B[0]; B[2] = btrunc(xl);
    B[3] = btrunc(yh); B[4] = B[3]; B[5] = btrunc(yl);
    B[6] = btrunc(zh); B[7] = B[6]; B[8] = btrunc(zl);
    B[9] = btrunc(qh); B[10] = btrunc(ql);
    B[11] = B[12] = B[13] = B[14] = B[15] = 0;

    sq[i] = q;
}

// grid = (NPTS/BROWS=64, TSPLIT=8, 2). Wave: two 32-row tiles x 2048-target sweep,
// 32x32x16 bf16 MFMA intrinsic (compiler-managed hazards), depth-2 B prefetch.
__global__ __launch_bounds__(BT, 4)
void chamfer_mfma(const unsigned short* __restrict__ Apack,
                  const unsigned short* __restrict__ Bpack,
                  const float* __restrict__ sq,
                  unsigned* __restrict__ out)
{
    const int dir = blockIdx.z;
    const unsigned short* A = Apack + (size_t)(dir ? NPTS : 0) * KS;
    const unsigned short* B = Bpack + (size_t)(dir ? 0 : NPTS) * KS;
    const float* s2 = sq + (dir ? NPTS : 0);
    unsigned* o = out + dir * NPTS;

    const int lane = threadIdx.x & 63;
    const int wv   = threadIdx.x >> 6;
    const int n32  = lane & 31;
    const int kh   = lane >> 5;         // k-slice half (0: k0..7, 1: k8..15)

    const int rbase = blockIdx.x * BROWS + wv * 64;

    const bf16x8 a0 = *(const bf16x8*)(A + (size_t)(rbase + n32) * KS + kh * 8);
    const bf16x8 a1 = *(const bf16x8*)(A + (size_t)(rbase + 32 + n32) * KS + kh * 8);

    f32x16 mn0, mn1, zc;
#pragma unroll
    for (int r = 0; r < 16; ++r) { mn0[r] = 1e30f; mn1[r] = 1e30f; zc[r] = 0.0f; }

    const unsigned short* Bl = B + (size_t)(blockIdx.y * SWEEP + n32) * KS + kh * 8;
#define BTILE(t) (*(const bf16x8*)(Bl + (size_t)(t) * 32 * KS))

#define PROC(bb)                                                                   \
    {                                                                              \
        f32x16 c0 = __builtin_amdgcn_mfma_f32_32x32x16_bf16(a0, (bb), zc, 0, 0, 0);\
        f32x16 c1 = __builtin_amdgcn_mfma_f32_32x32x16_bf16(a1, (bb), zc, 0, 0, 0);\
        _Pragma("unroll")                                                          \
        for (int r = 0; r < 16; ++r) mn0[r] = fminf(mn0[r], c0[r]);                \
        _Pragma("unroll")                                                          \
        for (int r = 0; r < 16; ++r) mn1[r] = fminf(mn1[r], c1[r]);                \
    }

    bf16x8 b0 = BTILE(0);
    bf16x8 b1 = BTILE(1);
#pragma unroll 2
    for (int t = 0; t < NTILE - 2; t += 2) {
        bf16x8 n0 = BTILE(t + 2);       // depth-2 prefetch: issued ~140 cycles
        bf16x8 n1 = BTILE(t + 3);       // before consumption
        PROC(b0);
        PROC(b1);
        b0 = n0;
        b1 = n1;
    }
    PROC(b0);
    PROC(b1);

    // column reduce across the 32 lanes of each half-wave group
#pragma unroll
    for (int r = 0; r < 16; ++r) {
        float v0 = mn0[r], v1 = mn1[r];
        v0 = fminf(v0, __shfl_xor(v0, 1, 32));  v1 = fminf(v1, __shfl_xor(v1, 1, 32));
        v0 = fminf(v0, __shfl_xor(v0, 2, 32));  v1 = fminf(v1, __shfl_xor(v1, 2, 32));
        v0 = fminf(v0, __shfl_xor(v0, 4, 32));  v1 = fminf(v1, __shfl_xor(v1, 4, 32));
        v0 = fminf(v0, __shfl_xor(v0, 8, 32));  v1 = fminf(v1, __shfl_xor(v1, 8, 32));
        v0 = fminf(v0, __shfl_xor(v0, 16, 32)); v1 = fminf(v1, __shfl_xor(v1, 16, 32));
        mn0[r] = v0; mn1[r] = v1;
    }

    if (n32 == 0) {
        // C/D map (32x32, r2-verified): col = lane&31, row = (r&3) + 8*(r>>2) + 4*kh
#pragma unroll
        for (int r = 0; r < 16; ++r) {
            int row0 = rbase + (r & 3) + 8 * (r >> 2) + 4 * kh;
            float d0 = fmaxf(mn0[r] + s2[row0], 0.0f);
            atomicMin(&o[row0], __float_as_uint(d0));
            int row1 = row0 + 32;
            float d1 = fmaxf(mn1[r] + s2[row1], 0.0f);
            atomicMin(&o[row1], __float_as_uint(d1));
        }
    }
#undef PROC
#undef BTILE
}

extern "C" void kernel_launch(void* const* d_in, const int* in_sizes, int n_in,
                              void* d_out, int out_size, void* d_ws, size_t ws_size,
                              hipStream_t stream) {
    const float* s = (const float*)d_in[0];
    const float* t = (const float*)d_in[1];

    unsigned short* Apack = (unsigned short*)d_ws;                 // 1 MB
    unsigned short* Bpack = Apack + (size_t)2 * NPTS * KS;         // 1 MB
    float* sq = (float*)(Bpack + (size_t)2 * NPTS * KS);           // 128 KB

    chamfer_pack<<<(2 * NPTS + BT - 1) / BT, BT, 0, stream>>>(
        s, t, Apack, Bpack, sq, (unsigned*)d_out);

    dim3 grid(NPTS / BROWS, TSPLIT, 2);
    chamfer_mfma<<<grid, BT, 0, stream>>>(Apack, Bpack, sq, (unsigned*)d_out);
}